// Round 3
// baseline (80.672 us; speedup 1.0000x reference)
//
#include <hip/hip_runtime.h>

typedef __attribute__((ext_vector_type(8))) short short8;
typedef __attribute__((ext_vector_type(4))) float f32x4;
typedef __attribute__((ext_vector_type(4))) int i32x4;

// fp32 -> bf16 round-to-nearest-even
__device__ __forceinline__ unsigned short f2bf(float f) {
  unsigned u = __builtin_bit_cast(unsigned, f);
  u += 0x7fffu + ((u >> 16) & 1u);
  return (unsigned short)(u >> 16);
}

// ---------------------------------------------------------------------------
// prep: blocks [0,512): per-(b,i) stats + exact fp32 copies.
//   - out0 cols 0..127   = user (exact fp32)
//   - out1 cols 0..127   = RIS  (exact fp32)
//   - m1b/m2b (bf16), am (i32), mean_bf (bf16), ris_bf (bf16)
// blocks [512,1664): W1..W4 fp32 -> bf16, MFMA B-fragment swizzle.
// ---------------------------------------------------------------------------
__global__ __launch_bounds__(256) void prep(
    const float* __restrict__ user, const float* __restrict__ ris,
    const float* __restrict__ W1, const float* __restrict__ W2,
    const float* __restrict__ W3, const float* __restrict__ W4,
    unsigned short* __restrict__ m1b, unsigned short* __restrict__ m2b,
    int* __restrict__ am, unsigned short* __restrict__ meanb,
    unsigned short* __restrict__ risb,
    unsigned short* __restrict__ W1f, unsigned short* __restrict__ W2f,
    unsigned short* __restrict__ W3f, unsigned short* __restrict__ W4f,
    float* __restrict__ out0, float* __restrict__ out1) {
  if (blockIdx.x < 512) {
    int idx = blockIdx.x * 256 + threadIdx.x;  // 0..131071 (B*IN)
    int b = idx >> 7, i = idx & 127;
    const float* up = user + (size_t)(b * 64) * 128 + i;
    float* op = out0 + (size_t)(b * 64) * 384 + i;
    float s = 0.f, m1 = -3.402823466e38f, m2 = -3.402823466e38f;
    int amx = 0;
    #pragma unroll 8
    for (int k = 0; k < 64; ++k) {
      float u = up[(size_t)k * 128];
      op[(size_t)k * 384] = u;   // exact fp32 copy
      s += u;
      if (u > m1) { m2 = m1; m1 = u; amx = k; }
      else if (u > m2) { m2 = u; }
    }
    m1b[idx] = f2bf(m1);
    m2b[idx] = f2bf(m2);
    am[idx] = amx;
    meanb[idx] = f2bf(s * (1.f / 64.f));
    float rv = ris[idx];
    out1[(size_t)b * 384 + i] = rv;  // exact fp32 copy
    risb[idx] = f2bf(rv);
  } else {
    int idx = (blockIdx.x - 512) * 256 + threadIdx.x;  // 0..294911
    const float* src; unsigned short* dst; int kb; int rel;
    if (idx < 98304)        { src = W1; dst = W1f; kb = 12; rel = idx; }
    else if (idx < 163840)  { src = W2; dst = W2f; kb = 8;  rel = idx - 98304; }
    else if (idx < 229376)  { src = W3; dst = W3f; kb = 8;  rel = idx - 163840; }
    else                    { src = W4; dst = W4f; kb = 8;  rel = idx - 229376; }
    int kk = rel >> 8, n = rel & 255;
    int lane = (n & 15) | (((kk >> 3) & 3) << 4);
    int di = (((n >> 4) * kb + (kk >> 5)) * 64 + lane) * 8 + (kk & 7);
    dst[di] = f2bf(src[rel]);
  }
}

// ---------------------------------------------------------------------------
// fused 2-layer MLP, 64-row x 256-col tile, 4 waves (N-split), bf16 MFMA.
// A-fragments loaded DIRECTLY from global (no LDS, no layer-1 barriers).
// MODE 0: rows = (b,k) pairs; A = [user fp32 | loo(stats) | ris bcast], K1=384.
// MODE 1: rows = b;          A = [ris_bf | mean_bf], K1=256.
// H (layer-1 out) lives in XOR-swizzled LDS; single __syncthreads.
// ---------------------------------------------------------------------------
template<int MODE>
__device__ __forceinline__ void mlp_body(
    int bx, unsigned short* __restrict__ Hb,
    const float* __restrict__ user,
    const unsigned short* __restrict__ m1b, const unsigned short* __restrict__ m2b,
    const int* __restrict__ am,
    const unsigned short* __restrict__ risb, const unsigned short* __restrict__ meanb,
    const unsigned short* __restrict__ Wa, const unsigned short* __restrict__ Wb,
    const float* __restrict__ ba, const float* __restrict__ bb,
    float* __restrict__ out) {
  constexpr int NFS = (MODE == 0) ? 12 : 8;   // K1/32 fragment-steps

  const int tid = threadIdx.x;
  const int lane = tid & 63, wn = tid >> 6;   // 4 waves, N-split (64 cols each)
  const int row0 = bx * 64;
  const int r = lane & 15;                    // A-frag row within 16
  const int k8 = (lane >> 4) * 8;             // A-frag k-offset within 32

  f32x4 acc[4][4];
  #pragma unroll
  for (int a = 0; a < 4; ++a)
    #pragma unroll
    for (int q = 0; q < 4; ++q) acc[a][q] = (f32x4)0.f;

  // ---- layer 1: A(64xK1) @ Wa(K1x256), A-frags straight from global ----
  #pragma unroll
  for (int fs = 0; fs < NFS; ++fs) {
    short8 af[4];
    if constexpr (MODE == 0) {
      if (fs < 4) {               // user chunk (fp32 -> bf16 in-reg)
        #pragma unroll
        for (int mf = 0; mf < 4; ++mf) {
          const float* p = &user[(size_t)(row0 + mf * 16 + r) * 128 + fs * 32 + k8];
          f32x4 t0 = *(const f32x4*)p;
          f32x4 t1 = *(const f32x4*)(p + 4);
          short8 t;
          #pragma unroll
          for (int j = 0; j < 4; ++j) { t[j] = (short)f2bf(t0[j]); t[4 + j] = (short)f2bf(t1[j]); }
          af[mf] = t;
        }
      } else if (fs < 8) {        // leave-one-out max chunk from stats
        int c0 = bx * 128 + (fs - 4) * 32 + k8;
        short8 m1v = *(const short8*)&m1b[c0];
        short8 m2v = *(const short8*)&m2b[c0];
        i32x4 a0 = *(const i32x4*)&am[c0];
        i32x4 a1 = *(const i32x4*)&am[c0 + 4];
        #pragma unroll
        for (int mf = 0; mf < 4; ++mf) {
          int rr = mf * 16 + r;
          short8 t;
          #pragma unroll
          for (int j = 0; j < 4; ++j) {
            t[j]     = (a0[j] == rr) ? m2v[j]     : m1v[j];
            t[4 + j] = (a1[j] == rr) ? m2v[4 + j] : m1v[4 + j];
          }
          af[mf] = t;
        }
      } else {                    // RIS broadcast chunk (same for all rows)
        short8 v = *(const short8*)&risb[bx * 128 + (fs - 8) * 32 + k8];
        #pragma unroll
        for (int mf = 0; mf < 4; ++mf) af[mf] = v;
      }
    } else {
      const unsigned short* src = (fs < 4) ? risb : meanb;
      #pragma unroll
      for (int mf = 0; mf < 4; ++mf)
        af[mf] = *(const short8*)&src[(size_t)(row0 + mf * 16 + r) * 128 + (fs & 3) * 32 + k8];
    }
    short8 bfr[4];
    #pragma unroll
    for (int nf = 0; nf < 4; ++nf)
      bfr[nf] = *(const short8*)&Wa[(size_t)(((wn * 4 + nf) * NFS + fs) * 64 + lane) * 8];
    #pragma unroll
    for (int mf = 0; mf < 4; ++mf)
      #pragma unroll
      for (int nf = 0; nf < 4; ++nf)
        acc[mf][nf] = __builtin_amdgcn_mfma_f32_16x16x32_bf16(af[mf], bfr[nf], acc[mf][nf], 0, 0, 0);
  }

  // ---- layer-1 epilogue: bias + relu -> H (bf16, XOR-swizzled LDS) ----
  float bav[4];
  #pragma unroll
  for (int nf = 0; nf < 4; ++nf) bav[nf] = ba[wn * 64 + nf * 16 + (lane & 15)];
  #pragma unroll
  for (int mf = 0; mf < 4; ++mf)
    #pragma unroll
    for (int nf = 0; nf < 4; ++nf)
      #pragma unroll
      for (int j = 0; j < 4; ++j) {
        int rr = mf * 16 + ((lane >> 4) * 4) + j;
        int col = wn * 64 + nf * 16 + (lane & 15);
        int c = col >> 3;
        Hb[rr * 256 + ((c ^ (rr & 7)) << 3) + (col & 7)] =
            f2bf(fmaxf(acc[mf][nf][j] + bav[nf], 0.f));
      }
  __syncthreads();

  // ---- layer 2: H(64x256) @ Wb(256x256) ----
  #pragma unroll
  for (int a = 0; a < 4; ++a)
    #pragma unroll
    for (int q = 0; q < 4; ++q) acc[a][q] = (f32x4)0.f;
  #pragma unroll
  for (int kc = 0; kc < 8; ++kc) {
    short8 af[4], bfr[4];
    #pragma unroll
    for (int mf = 0; mf < 4; ++mf) {
      int rr = mf * 16 + (lane & 15);
      int c = kc * 4 + (lane >> 4);
      af[mf] = *(const short8*)(Hb + rr * 256 + ((c ^ (rr & 7)) << 3));
    }
    #pragma unroll
    for (int nf = 0; nf < 4; ++nf)
      bfr[nf] = *(const short8*)&Wb[(size_t)(((wn * 4 + nf) * 8 + kc) * 64 + lane) * 8];
    #pragma unroll
    for (int mf = 0; mf < 4; ++mf)
      #pragma unroll
      for (int nf = 0; nf < 4; ++nf)
        acc[mf][nf] = __builtin_amdgcn_mfma_f32_16x16x32_bf16(af[mf], bfr[nf], acc[mf][nf], 0, 0, 0);
  }

  // ---- layer-2 epilogue: bias, fp32 store to out cols 128..383 ----
  float bbv[4];
  #pragma unroll
  for (int nf = 0; nf < 4; ++nf) bbv[nf] = bb[wn * 64 + nf * 16 + (lane & 15)];
  #pragma unroll
  for (int mf = 0; mf < 4; ++mf)
    #pragma unroll
    for (int nf = 0; nf < 4; ++nf)
      #pragma unroll
      for (int j = 0; j < 4; ++j) {
        int rr = mf * 16 + ((lane >> 4) * 4) + j;
        int col = wn * 64 + nf * 16 + (lane & 15);
        out[(size_t)(row0 + rr) * 384 + 128 + col] = acc[mf][nf][j] + bbv[nf];
      }
}

__global__ __launch_bounds__(256, 4) void fused(
    const float* __restrict__ user,
    const unsigned short* __restrict__ m1b, const unsigned short* __restrict__ m2b,
    const int* __restrict__ am,
    const unsigned short* __restrict__ risb, const unsigned short* __restrict__ meanb,
    const unsigned short* __restrict__ W1f, const unsigned short* __restrict__ W2f,
    const unsigned short* __restrict__ W3f, const unsigned short* __restrict__ W4f,
    const float* __restrict__ b1, const float* __restrict__ b2,
    const float* __restrict__ b3, const float* __restrict__ b4,
    float* __restrict__ out0, float* __restrict__ out1) {
  __shared__ unsigned short Hb[64 * 256];   // 32 KiB, XOR-swizzled
  if (blockIdx.x < 1024)
    mlp_body<0>(blockIdx.x, Hb, user, m1b, m2b, am, risb, meanb,
                W1f, W2f, b1, b2, out0);
  else
    mlp_body<1>(blockIdx.x - 1024, Hb, user, m1b, m2b, am, risb, meanb,
                W3f, W4f, b3, b4, out1);
}

// ---------------------------------------------------------------------------
extern "C" void kernel_launch(void* const* d_in, const int* in_sizes, int n_in,
                              void* d_out, int out_size, void* d_ws, size_t ws_size,
                              hipStream_t stream) {
  const float* user = (const float*)d_in[0];
  const float* ris  = (const float*)d_in[1];
  const float* W1 = (const float*)d_in[4];
  const float* b1 = (const float*)d_in[5];
  const float* W2 = (const float*)d_in[6];
  const float* b2 = (const float*)d_in[7];
  const float* W3 = (const float*)d_in[8];
  const float* b3 = (const float*)d_in[9];
  const float* W4 = (const float*)d_in[10];
  const float* b4 = (const float*)d_in[11];

  float* out0 = (float*)d_out;                         // (65536, 384)
  float* out1 = out0 + (size_t)65536 * 384;            // (1024, 384)

  char* ws = (char*)d_ws;
  unsigned short* m1b   = (unsigned short*)(ws);            // 131072 bf16
  unsigned short* m2b   = (unsigned short*)(ws + 262144);   // 131072 bf16
  int*            amv   = (int*)(ws + 524288);              // 131072 i32
  unsigned short* meanb = (unsigned short*)(ws + 1048576);  // 131072 bf16
  unsigned short* risb  = (unsigned short*)(ws + 1310720);  // 131072 bf16
  unsigned short* W1f   = (unsigned short*)(ws + 1572864);  // 98304 bf16
  unsigned short* W2f   = (unsigned short*)(ws + 1769472);  // 65536 bf16
  unsigned short* W3f   = (unsigned short*)(ws + 1900544);  // 65536 bf16
  unsigned short* W4f   = (unsigned short*)(ws + 2031616);  // 65536 bf16

  hipLaunchKernelGGL(prep, dim3(1664), dim3(256), 0, stream,
                     user, ris, W1, W2, W3, W4,
                     m1b, m2b, amv, meanb, risb,
                     W1f, W2f, W3f, W4f, out0, out1);
  hipLaunchKernelGGL(fused, dim3(1040), dim3(256), 0, stream,
                     user, m1b, m2b, amv, risb, meanb,
                     W1f, W2f, W3f, W4f, b1, b2, b3, b4, out0, out1);
}